// Round 4
// baseline (158.825 us; speedup 1.0000x reference)
//
#include <hip/hip_runtime.h>
#include <math.h>

#define D 64
#define CH 256              // owned edges per block
#define HALO 32             // >= max idx_vi segment length (actual ~10)
#define WSZ (CH + HALO)     // edge window per block (288)
#define NT (WSZ / 32)       // phase-A iterations (9, odd — tail handled explicitly)

// ---------------- K0: zero out[] and row_sum[] ----------------
__global__ void k_zero(float4* __restrict__ out4, float* __restrict__ row_sum,
                       int BN4, int Bn)
{
    const int i = blockIdx.x * 256 + threadIdx.x;
    if (i < BN4) out4[i] = make_float4(0.f, 0.f, 0.f, 0.f);
    if (i < Bn) row_sum[i] = 0.f;
}

// per-edge logit core (out_b dropped: it shifts all logits by a constant,
// which the segment softmax cancels exactly)
__device__ __forceinline__ float edge_logit(
    const float4 a, const float4 c, const float4 ui, const float4 uj,
    const float4 r, const float* Wf, const float* Bvf, const float* Owf)
{
    const float* ap = (const float*)&a;  const float* cp = (const float*)&c;
    const float* up = (const float*)&ui; const float* vp = (const float*)&uj;
    const float* rp = (const float*)&r;
    float acc = 0.f;
    #pragma unroll
    for (int k4 = 0; k4 < 4; ++k4) {
        const float hcvi = ap[k4], hcvj = cp[k4], huvi = up[k4], huvj = vp[k4], rr = rp[k4];
        const float hcr = hcvi * rr, hur = huvi * rr;
        float f = Bvf[k4];
        f += Wf[0*4+k4] * (hcvi * hcvj);
        f += Wf[1*4+k4] * (hcr  * hcvj);
        f += Wf[2*4+k4] * (hcvi * huvj);
        f += Wf[3*4+k4] * (hcr  * huvj);
        f += Wf[4*4+k4] * (huvi * hcvj);
        f += Wf[5*4+k4] * (hur  * hcvj);
        f += Wf[6*4+k4] * (huvi * huvj);
        f += Wf[7*4+k4] * (hur  * huvj);
        acc += fmaxf(f, 0.f) * Owf[k4];
    }
    return acc;
}

// issue the two FAR gathers (hc[e2vj], hu[vj] — random rows, ~HBM/L3 latency)
// for iteration T, into named double-buffer registers.
#define FAR_ISSUE(C0, C1, UJ0, UJ1, T)                                    \
    {                                                                     \
        const int jj0 = (T) * 32 + wv * 8 + g;                            \
        const int jj1 = jj0 + 4;                                          \
        const int jc0 = (jj0 < Wc) ? jj0 : (Wc - 1);                      \
        const int jc1 = (jj1 < Wc) ? jj1 : (Wc - 1);                      \
        const int e2vj0 = s_sel[jc0 * 8 + 7];                             \
        const int vjg0  = s_sel[jc0 * 8 + 2];                             \
        const int e2vj1 = s_sel[jc1 * 8 + 7];                             \
        const int vjg1  = s_sel[jc1 * 8 + 2];                             \
        C0  = hc4[(size_t)e2vj0 * 16 + d16];                              \
        UJ0 = hu4[(size_t)vjg0  * 16 + d16];                              \
        C1  = hc4[(size_t)e2vj1 * 16 + d16];                              \
        UJ1 = hu4[(size_t)vjg1  * 16 + d16];                              \
    }

// NEAR gathers (hc[e2vi], hu[vi] near-sequential thanks to (idx,vi) sort;
// re 128KB cache-hot) + compute + 16-lane reduce + LDS store, for iter T,
// consuming the FAR buffer issued one iteration earlier.
#define COMPUTE_STEP(C0, C1, UJ0, UJ1, T)                                 \
    {                                                                     \
        const int jj0 = (T) * 32 + wv * 8 + g;                            \
        const int jj1 = jj0 + 4;                                          \
        const bool v0 = (jj0 < Wc);                                       \
        const bool v1 = (jj1 < Wc);                                       \
        const int jc0 = v0 ? jj0 : (Wc - 1);                              \
        const int jc1 = v1 ? jj1 : (Wc - 1);                              \
        const int e2vi0 = s_sel[jc0 * 8 + 6];                             \
        const int vig0  = s_sel[jc0 * 8 + 1];                             \
        const int rel0  = s_sel[jc0 * 8 + 3];                             \
        const int ivi0  = s_sel[jc0 * 8 + 4];                             \
        const int e2vi1 = s_sel[jc1 * 8 + 6];                             \
        const int vig1  = s_sel[jc1 * 8 + 1];                             \
        const int rel1  = s_sel[jc1 * 8 + 3];                             \
        const int ivi1  = s_sel[jc1 * 8 + 4];                             \
        const float4 a0  = hc4[(size_t)e2vi0 * 16 + d16];                 \
        const float4 ui0 = hu4[(size_t)vig0  * 16 + d16];                 \
        const float4 r0  = re4[(size_t)rel0  * 16 + d16];                 \
        const float4 a1  = hc4[(size_t)e2vi1 * 16 + d16];                 \
        const float4 ui1 = hu4[(size_t)vig1  * 16 + d16];                 \
        const float4 r1  = re4[(size_t)rel1  * 16 + d16];                 \
        float acc0 = edge_logit(a0, C0, ui0, UJ0, r0, Wf, Bvf, Owf);      \
        float acc1 = edge_logit(a1, C1, ui1, UJ1, r1, Wf, Bvf, Owf);      \
        _Pragma("unroll")                                                 \
        for (int off = 8; off > 0; off >>= 1) {                           \
            acc0 += __shfl_xor(acc0, off, 64);                            \
            acc1 += __shfl_xor(acc1, off, 64);                            \
        }                                                                 \
        if (d16 == 0) {                                                   \
            if (v0) { s_logit[jj0] = acc0; s_ivi[jj0] = ivi0; }           \
            if (v1) { s_logit[jj1] = acc1; s_ivi[jj1] = ivi1; }           \
        }                                                                 \
    }

// ---------------- K1: fused logits + segment softmax + scatter + rowsum --------
// NOTE (round-2 lesson): no min-waves clause — forcing 8 waves/EU (VGPR<=64)
// spilled ~40 float4s to scratch (316 MB scratch writes, 5x regression).
__global__ __launch_bounds__(256) void k_fused(
    const int* __restrict__ sel, const float* __restrict__ hc,
    const float* __restrict__ hu, const float* __restrict__ re,
    const float* __restrict__ wsm, const float* __restrict__ bias,
    const float* __restrict__ out_w,
    const float* __restrict__ na, const float* __restrict__ edges_y,
    float* __restrict__ out, float* __restrict__ row_sum,
    int E, int N)
{
    __shared__ int   s_sel[WSZ * 8];     // 9216 B: full sel rows for window
    __shared__ float s_logit[WSZ];
    __shared__ int   s_ivi[WSZ];         // dense idx_vi for stride-1 phase-B scans
    __shared__ float s_row[8];

    const int b0 = blockIdx.x * CH;
    const int Wc = min(WSZ, E - b0);     // valid edges in this window

    // ---------- Preload sel window (perfectly coalesced) ----------
    {
        const int nint = Wc * 8;
        const int* selw = sel + (size_t)b0 * 8;
        for (int i = threadIdx.x; i < nint; i += 256) s_sel[i] = selw[i];
    }
    if (threadIdx.x < 8) s_row[threadIdx.x] = 0.f;

    const int lane = threadIdx.x & 63;
    const int g    = lane >> 4;          // edge-group within wave (0..3)
    const int d16  = lane & 15;          // lane within group; d = d16*4 .. +3
    const int wv   = threadIdx.x >> 6;   // wave within block (0..3)

    // hoist constants into registers
    const float4* wsm4 = (const float4*)wsm;
    float4 Wk[8];
    #pragma unroll
    for (int k = 0; k < 8; ++k) Wk[k] = wsm4[k * 16 + d16];
    const float4 Bv = ((const float4*)bias)[d16];
    const float4 Ow = ((const float4*)out_w)[d16];
    const float* Wf  = (const float*)Wk;
    const float* Bvf = (const float*)&Bv;
    const float* Owf = (const float*)&Ow;

    const float4* hc4 = (const float4*)hc;
    const float4* hu4 = (const float4*)hu;
    const float4* re4 = (const float4*)re;

    __syncthreads();

    // ---------- Phase A: software-pipelined (far gathers 1 iter ahead) ----------
    float4 cA0, cA1, ujA0, ujA1;
    float4 cB0, cB1, ujB0, ujB1;

    FAR_ISSUE(cA0, cA1, ujA0, ujA1, 0);

    int t = 0;
    #pragma unroll 1
    for (; t + 2 < NT; t += 2) {
        FAR_ISSUE(cB0, cB1, ujB0, ujB1, t + 1);
        COMPUTE_STEP(cA0, cA1, ujA0, ujA1, t);
        FAR_ISSUE(cA0, cA1, ujA0, ujA1, t + 2);
        COMPUTE_STEP(cB0, cB1, ujB0, ujB1, t + 1);
    }
    // NT = 9 (odd): exactly one iteration remains, already issued into A
    COMPUTE_STEP(cA0, cA1, ujA0, ujA1, NT - 1);

    __syncthreads();

    // ---------- Phase B: block-local segment softmax + scatter ----------
    const int ivi_prev = (b0 > 0) ? sel[((size_t)b0 - 1) * 8 + 4] : -1;

    for (int j = threadIdx.x; j < Wc; j += 256) {
        const int myivi = s_ivi[j];

        int s = j;
        while (s > 0 && s_ivi[s - 1] == myivi) --s;
        const bool genuine = (s > 0) || (myivi != ivi_prev);
        if (!genuine || s >= CH) continue;      // segment owned by another block

        int en = j + 1;
        while (en < Wc && s_ivi[en] == myivi) ++en;

        float m = s_logit[j];
        for (int i = s; i < en; ++i) m = fmaxf(m, s_logit[i]);
        float sum = 0.f;
        for (int i = s; i < en; ++i) sum += __expf(s_logit[i] - m);

        const int idx = s_sel[j * 8 + 0];
        const int vi  = s_sel[j * 8 + 1];
        const int vj  = s_sel[j * 8 + 2];
        const float ta = na[(size_t)idx * N + vi]
                       * (__expf(s_logit[j] - m) / sum) * edges_y[b0 + j];

        atomicAdd(out + (size_t)idx * N + vj, ta);
        if (idx < 8) atomicAdd(&s_row[idx], ta);
        else         atomicAdd(row_sum + idx, ta);
    }

    __syncthreads();
    if (threadIdx.x < 8) {
        const float v = s_row[threadIdx.x];
        if (v != 0.f) atomicAdd(row_sum + threadIdx.x, v);
    }
}

// ---------------- K4: normalize rows (float4, 2D grid) ----------------
__global__ void k_norm(float4* __restrict__ out, const float* __restrict__ row_sum, int N4) {
    const int col = blockIdx.x * blockDim.x + threadIdx.x;
    const int row = blockIdx.y;
    if (col < N4) {
        const float inv = 1.f / row_sum[row];
        const size_t i = (size_t)row * N4 + col;
        float4 v = out[i];
        v.x *= inv; v.y *= inv; v.z *= inv; v.w *= inv;
        out[i] = v;
    }
}

extern "C" void kernel_launch(void* const* d_in, const int* in_sizes, int n_in,
                              void* d_out, int out_size, void* d_ws, size_t ws_size,
                              hipStream_t stream)
{
    const float* na    = (const float*)d_in[0];   // (B,N)
    const int*   sel   = (const int*)  d_in[1];   // (E,8)
    const float* ey    = (const float*)d_in[2];   // (E,)
    const float* hc    = (const float*)d_in[3];   // (n_visited, D)
    const float* hu    = (const float*)d_in[4];   // (1,N,D)
    const float* re    = (const float*)d_in[5];   // (R,D)
    const float* wsm   = (const float*)d_in[6];   // (8,D)
    const float* bias  = (const float*)d_in[7];   // (D,)
    const float* ow    = (const float*)d_in[8];   // (D,)
    // d_in[9] (out_b) intentionally unused: constant logit shift, softmax-invariant

    float* out = (float*)d_out;

    const int E  = in_sizes[2];
    const int N  = in_sizes[4] / D;   // hidden_uncon = N*D
    const int BN = in_sizes[0];       // B*N
    const int Bn = BN / N;

    float* row_sum = (float*)d_ws;

    const int N4  = N / 4;
    const int BN4 = BN / 4;

    k_zero<<<(BN4 + 255) / 256, 256, 0, stream>>>((float4*)out, row_sum, BN4, Bn);

    const int nblk = (E + CH - 1) / CH;
    k_fused<<<nblk, 256, 0, stream>>>(sel, hc, hu, re, wsm, bias, ow,
                                      na, ey, out, row_sum, E, N);

    dim3 ngrid((N4 + 255) / 256, Bn);
    k_norm<<<ngrid, 256, 0, stream>>>((float4*)out, row_sum, N4);
}

// Round 5
// 152.968 us; speedup vs baseline: 1.0383x; 1.0383x over previous
//
#include <hip/hip_runtime.h>
#include <math.h>

#define D 64
#define CH 256              // owned edges per block
#define HALO 32             // >= max idx_vi segment length (actual ~10)
#define WSZ (CH + HALO)     // edge window per block (288)
#define NT (WSZ / 32)       // phase-A iterations (9)

// ---------------- K0: zero out[] and row_sum[] ----------------
__global__ void k_zero(float4* __restrict__ out4, float* __restrict__ row_sum,
                       int BN4, int Bn)
{
    const int i = blockIdx.x * 256 + threadIdx.x;
    if (i < BN4) out4[i] = make_float4(0.f, 0.f, 0.f, 0.f);
    if (i < Bn) row_sum[i] = 0.f;
}

// per-edge logit core (out_b dropped: constant logit shift, softmax-invariant)
__device__ __forceinline__ float edge_logit(
    const float4 a, const float4 c, const float4 ui, const float4 uj,
    const float4 r, const float* Wf, const float* Bvf, const float* Owf)
{
    const float* ap = (const float*)&a;  const float* cp = (const float*)&c;
    const float* up = (const float*)&ui; const float* vp = (const float*)&uj;
    const float* rp = (const float*)&r;
    float acc = 0.f;
    #pragma unroll
    for (int k4 = 0; k4 < 4; ++k4) {
        const float hcvi = ap[k4], hcvj = cp[k4], huvi = up[k4], huvj = vp[k4], rr = rp[k4];
        const float hcr = hcvi * rr, hur = huvi * rr;
        float f = Bvf[k4];
        f += Wf[0*4+k4] * (hcvi * hcvj);
        f += Wf[1*4+k4] * (hcr  * hcvj);
        f += Wf[2*4+k4] * (hcvi * huvj);
        f += Wf[3*4+k4] * (hcr  * huvj);
        f += Wf[4*4+k4] * (huvi * hcvj);
        f += Wf[5*4+k4] * (hur  * hcvj);
        f += Wf[6*4+k4] * (huvi * huvj);
        f += Wf[7*4+k4] * (hur  * huvj);
        acc += fmaxf(f, 0.f) * Owf[k4];
    }
    return acc;
}

// Issue NEAR gathers for iter T (vi-side: near-sequential rows; re: L2-hot).
// T may exceed the window: indices clamp to Wc-1 (harmless dummy loads).
#define NEAR_ISSUE(A0, UI0, R0, A1, UI1, R1, T)                           \
    {                                                                     \
        const int jj0 = (T) * 32 + wv * 8 + g;                            \
        const int jj1 = jj0 + 4;                                          \
        const int jc0 = (jj0 < Wc) ? jj0 : (Wc - 1);                      \
        const int jc1 = (jj1 < Wc) ? jj1 : (Wc - 1);                      \
        A0  = hc4[(size_t)s_sel[jc0 * 8 + 6] * 16 + d16];                 \
        UI0 = hu4[(size_t)s_sel[jc0 * 8 + 1] * 16 + d16];                 \
        R0  = re4[(size_t)s_sel[jc0 * 8 + 3] * 16 + d16];                 \
        A1  = hc4[(size_t)s_sel[jc1 * 8 + 6] * 16 + d16];                 \
        UI1 = hu4[(size_t)s_sel[jc1 * 8 + 1] * 16 + d16];                 \
        R1  = re4[(size_t)s_sel[jc1 * 8 + 3] * 16 + d16];                 \
    }

// Issue FAR gathers for iter T (vj-side: random rows, L3/HBM latency).
#define FAR_ISSUE(C0, UJ0, C1, UJ1, T)                                    \
    {                                                                     \
        const int jj0 = (T) * 32 + wv * 8 + g;                            \
        const int jj1 = jj0 + 4;                                          \
        const int jc0 = (jj0 < Wc) ? jj0 : (Wc - 1);                      \
        const int jc1 = (jj1 < Wc) ? jj1 : (Wc - 1);                      \
        C0  = hc4[(size_t)s_sel[jc0 * 8 + 7] * 16 + d16];                 \
        UJ0 = hu4[(size_t)s_sel[jc0 * 8 + 2] * 16 + d16];                 \
        C1  = hc4[(size_t)s_sel[jc1 * 8 + 7] * 16 + d16];                 \
        UJ1 = hu4[(size_t)s_sel[jc1 * 8 + 2] * 16 + d16];                 \
    }

// Consume iter T's registers (loaded one iteration earlier -> oldest in the
// vmcnt queue -> compiler waits with vmcnt(10), keeping t+1's loads in flight).
#define COMPUTE(A0, UI0, R0, A1, UI1, R1, C0, UJ0, C1, UJ1, T)            \
    {                                                                     \
        const int jj0 = (T) * 32 + wv * 8 + g;                            \
        const int jj1 = jj0 + 4;                                          \
        const bool v0 = (jj0 < Wc);                                       \
        const bool v1 = (jj1 < Wc);                                       \
        const int jc0 = v0 ? jj0 : (Wc - 1);                              \
        const int jc1 = v1 ? jj1 : (Wc - 1);                              \
        float acc0 = edge_logit(A0, C0, UI0, UJ0, R0, Wf, Bvf, Owf);      \
        float acc1 = edge_logit(A1, C1, UI1, UJ1, R1, Wf, Bvf, Owf);      \
        _Pragma("unroll")                                                 \
        for (int off = 8; off > 0; off >>= 1) {                           \
            acc0 += __shfl_xor(acc0, off, 64);                            \
            acc1 += __shfl_xor(acc1, off, 64);                            \
        }                                                                 \
        if (d16 == 0) {                                                   \
            if (v0) { s_logit[jj0] = acc0; s_ivi[jj0] = s_sel[jc0 * 8 + 4]; } \
            if (v1) { s_logit[jj1] = acc1; s_ivi[jj1] = s_sel[jc1 * 8 + 4]; } \
        }                                                                 \
    }

// ---------------- K1: fused logits + segment softmax + scatter + rowsum --------
// Round-2 lesson: no min-waves clause (forcing VGPR<=64 spilled -> 5x regression).
__global__ __launch_bounds__(256) void k_fused(
    const int* __restrict__ sel, const float* __restrict__ hc,
    const float* __restrict__ hu, const float* __restrict__ re,
    const float* __restrict__ wsm, const float* __restrict__ bias,
    const float* __restrict__ out_w,
    const float* __restrict__ na, const float* __restrict__ edges_y,
    float* __restrict__ out, float* __restrict__ row_sum,
    int E, int N)
{
    __shared__ int   s_sel[WSZ * 8];     // full sel rows for window
    __shared__ float s_logit[WSZ];
    __shared__ int   s_ivi[WSZ];         // dense idx_vi for stride-1 phase-B scans
    __shared__ float s_row[8];

    const int b0 = blockIdx.x * CH;
    const int Wc = min(WSZ, E - b0);     // valid edges in this window

    // ---------- Preload sel window (perfectly coalesced) ----------
    {
        const int nint = Wc * 8;
        const int* selw = sel + (size_t)b0 * 8;
        for (int i = threadIdx.x; i < nint; i += 256) s_sel[i] = selw[i];
    }
    if (threadIdx.x < 8) s_row[threadIdx.x] = 0.f;

    const int lane = threadIdx.x & 63;
    const int g    = lane >> 4;          // edge-group within wave (0..3)
    const int d16  = lane & 15;          // lane within group; d = d16*4 .. +3
    const int wv   = threadIdx.x >> 6;   // wave within block (0..3)

    // hoist constants into registers
    const float4* wsm4 = (const float4*)wsm;
    float4 Wk[8];
    #pragma unroll
    for (int k = 0; k < 8; ++k) Wk[k] = wsm4[k * 16 + d16];
    const float4 Bv = ((const float4*)bias)[d16];
    const float4 Ow = ((const float4*)out_w)[d16];
    const float* Wf  = (const float*)Wk;
    const float* Bvf = (const float*)&Bv;
    const float* Owf = (const float*)&Ow;

    const float4* hc4 = (const float4*)hc;
    const float4* hu4 = (const float4*)hu;
    const float4* re4 = (const float4*)re;

    __syncthreads();

    // ---------- Phase A: fully software-pipelined (ALL gathers 1 iter ahead,
    //            issue-before-consume so vmcnt stays counted, never drained) ----
    float4 nA0a, nUI0a, nR0a, nA1a, nUI1a, nR1a;   // near buffer A
    float4 nA0b, nUI0b, nR0b, nA1b, nUI1b, nR1b;   // near buffer B
    float4 fC0a, fUJ0a, fC1a, fUJ1a;               // far buffer A
    float4 fC0b, fUJ0b, fC1b, fUJ1b;               // far buffer B

    NEAR_ISSUE(nA0a, nUI0a, nR0a, nA1a, nUI1a, nR1a, 0);
    FAR_ISSUE (fC0a, fUJ0a, fC1a, fUJ1a, 0);

    int t = 0;
    #pragma unroll 1
    for (; t + 1 < NT; t += 2) {
        NEAR_ISSUE(nA0b, nUI0b, nR0b, nA1b, nUI1b, nR1b, t + 1);
        FAR_ISSUE (fC0b, fUJ0b, fC1b, fUJ1b, t + 1);
        COMPUTE   (nA0a, nUI0a, nR0a, nA1a, nUI1a, nR1a,
                   fC0a, fUJ0a, fC1a, fUJ1a, t);
        NEAR_ISSUE(nA0a, nUI0a, nR0a, nA1a, nUI1a, nR1a, t + 2);
        FAR_ISSUE (fC0a, fUJ0a, fC1a, fUJ1a, t + 2);
        COMPUTE   (nA0b, nUI0b, nR0b, nA1b, nUI1b, nR1b,
                   fC0b, fUJ0b, fC1b, fUJ1b, t + 1);
    }
    // NT = 9 (odd): one iteration remains, its data already in buffer A
    COMPUTE(nA0a, nUI0a, nR0a, nA1a, nUI1a, nR1a,
            fC0a, fUJ0a, fC1a, fUJ1a, NT - 1);

    __syncthreads();

    // ---------- Phase B: block-local segment softmax + scatter ----------
    const int ivi_prev = (b0 > 0) ? sel[((size_t)b0 - 1) * 8 + 4] : -1;

    for (int j = threadIdx.x; j < Wc; j += 256) {
        const int myivi = s_ivi[j];

        int s = j;
        while (s > 0 && s_ivi[s - 1] == myivi) --s;
        const bool genuine = (s > 0) || (myivi != ivi_prev);
        if (!genuine || s >= CH) continue;      // segment owned by another block

        int en = j + 1;
        while (en < Wc && s_ivi[en] == myivi) ++en;

        float m = s_logit[j];
        for (int i = s; i < en; ++i) m = fmaxf(m, s_logit[i]);
        float sum = 0.f;
        for (int i = s; i < en; ++i) sum += __expf(s_logit[i] - m);

        const int idx = s_sel[j * 8 + 0];
        const int vi  = s_sel[j * 8 + 1];
        const int vj  = s_sel[j * 8 + 2];
        const float ta = na[(size_t)idx * N + vi]
                       * (__expf(s_logit[j] - m) / sum) * edges_y[b0 + j];

        atomicAdd(out + (size_t)idx * N + vj, ta);
        if (idx < 8) atomicAdd(&s_row[idx], ta);
        else         atomicAdd(row_sum + idx, ta);
    }

    __syncthreads();
    if (threadIdx.x < 8) {
        const float v = s_row[threadIdx.x];
        if (v != 0.f) atomicAdd(row_sum + threadIdx.x, v);
    }
}

// ---------------- K4: normalize rows (float4, 2D grid) ----------------
__global__ void k_norm(float4* __restrict__ out, const float* __restrict__ row_sum, int N4) {
    const int col = blockIdx.x * blockDim.x + threadIdx.x;
    const int row = blockIdx.y;
    if (col < N4) {
        const float inv = 1.f / row_sum[row];
        const size_t i = (size_t)row * N4 + col;
        float4 v = out[i];
        v.x *= inv; v.y *= inv; v.z *= inv; v.w *= inv;
        out[i] = v;
    }
}

extern "C" void kernel_launch(void* const* d_in, const int* in_sizes, int n_in,
                              void* d_out, int out_size, void* d_ws, size_t ws_size,
                              hipStream_t stream)
{
    const float* na    = (const float*)d_in[0];   // (B,N)
    const int*   sel   = (const int*)  d_in[1];   // (E,8)
    const float* ey    = (const float*)d_in[2];   // (E,)
    const float* hc    = (const float*)d_in[3];   // (n_visited, D)
    const float* hu    = (const float*)d_in[4];   // (1,N,D)
    const float* re    = (const float*)d_in[5];   // (R,D)
    const float* wsm   = (const float*)d_in[6];   // (8,D)
    const float* bias  = (const float*)d_in[7];   // (D,)
    const float* ow    = (const float*)d_in[8];   // (D,)
    // d_in[9] (out_b) intentionally unused: constant logit shift, softmax-invariant

    float* out = (float*)d_out;

    const int E  = in_sizes[2];
    const int N  = in_sizes[4] / D;   // hidden_uncon = N*D
    const int BN = in_sizes[0];       // B*N
    const int Bn = BN / N;

    float* row_sum = (float*)d_ws;

    const int N4  = N / 4;
    const int BN4 = BN / 4;

    k_zero<<<(BN4 + 255) / 256, 256, 0, stream>>>((float4*)out, row_sum, BN4, Bn);

    const int nblk = (E + CH - 1) / CH;
    k_fused<<<nblk, 256, 0, stream>>>(sel, hc, hu, re, wsm, bias, ow,
                                      na, ey, out, row_sum, E, N);

    dim3 ngrid((N4 + 255) / 256, Bn);
    k_norm<<<ngrid, 256, 0, stream>>>((float4*)out, row_sum, N4);
}

// Round 7
// 147.174 us; speedup vs baseline: 1.0792x; 1.0394x over previous
//
#include <hip/hip_runtime.h>
#include <math.h>

#define D 64
#define CH 256              // owned edges per block
#define HALO 32             // >= max idx_vi segment length (actual ~10)
#define WSZ (CH + HALO)     // edge window per block (288)
#define NT (WSZ / 32)       // phase-A iterations (9)

// ---------------- K0: zero out[] and row_sum[] ----------------
__global__ void k_zero(float4* __restrict__ out4, float* __restrict__ row_sum,
                       int BN4, int Bn)
{
    const int i = blockIdx.x * 256 + threadIdx.x;
    if (i < BN4) out4[i] = make_float4(0.f, 0.f, 0.f, 0.f);
    if (i < Bn) row_sum[i] = 0.f;
}

// per-edge logit core (out_b dropped: constant logit shift, softmax-invariant)
__device__ __forceinline__ float edge_logit(
    const float4 a, const float4 c, const float4 ui, const float4 uj,
    const float4 r, const float* Wf, const float* Bvf, const float* Owf)
{
    const float* ap = (const float*)&a;  const float* cp = (const float*)&c;
    const float* up = (const float*)&ui; const float* vp = (const float*)&uj;
    const float* rp = (const float*)&r;
    float acc = 0.f;
    #pragma unroll
    for (int k4 = 0; k4 < 4; ++k4) {
        const float hcvi = ap[k4], hcvj = cp[k4], huvi = up[k4], huvj = vp[k4], rr = rp[k4];
        const float hcr = hcvi * rr, hur = huvi * rr;
        float f = Bvf[k4];
        f += Wf[0*4+k4] * (hcvi * hcvj);
        f += Wf[1*4+k4] * (hcr  * hcvj);
        f += Wf[2*4+k4] * (hcvi * huvj);
        f += Wf[3*4+k4] * (hcr  * huvj);
        f += Wf[4*4+k4] * (huvi * hcvj);
        f += Wf[5*4+k4] * (hur  * hcvj);
        f += Wf[6*4+k4] * (huvi * huvj);
        f += Wf[7*4+k4] * (hur  * huvj);
        acc += fmaxf(f, 0.f) * Owf[k4];
    }
    return acc;
}

// Issue ALL 10 gathers for iter T into named double-buffer registers.
// T may exceed the window: indices clamp to Wc-1 (harmless dummy loads).
#define ISSUE(A0, UI0, R0, A1, UI1, R1, C0, UJ0, C1, UJ1, T)              \
    {                                                                     \
        const int jj0 = (T) * 32 + wv * 8 + g;                            \
        const int jj1 = jj0 + 4;                                          \
        const int jc0 = (jj0 < Wc) ? jj0 : (Wc - 1);                      \
        const int jc1 = (jj1 < Wc) ? jj1 : (Wc - 1);                      \
        A0  = hc4[(size_t)s_sel[jc0 * 8 + 6] * 16 + d16];                 \
        UI0 = hu4[(size_t)s_sel[jc0 * 8 + 1] * 16 + d16];                 \
        R0  = re4[(size_t)s_sel[jc0 * 8 + 3] * 16 + d16];                 \
        C0  = hc4[(size_t)s_sel[jc0 * 8 + 7] * 16 + d16];                 \
        UJ0 = hu4[(size_t)s_sel[jc0 * 8 + 2] * 16 + d16];                 \
        A1  = hc4[(size_t)s_sel[jc1 * 8 + 6] * 16 + d16];                 \
        UI1 = hu4[(size_t)s_sel[jc1 * 8 + 1] * 16 + d16];                 \
        R1  = re4[(size_t)s_sel[jc1 * 8 + 3] * 16 + d16];                 \
        C1  = hc4[(size_t)s_sel[jc1 * 8 + 7] * 16 + d16];                 \
        UJ1 = hu4[(size_t)s_sel[jc1 * 8 + 2] * 16 + d16];                 \
    }

// Consume iter T's registers (issued one iteration earlier -> oldest in the
// vmcnt queue -> the wait is vmcnt(10), keeping iter T+1's loads in flight).
#define COMPUTE(A0, UI0, R0, A1, UI1, R1, C0, UJ0, C1, UJ1, T)            \
    {                                                                     \
        const int jj0 = (T) * 32 + wv * 8 + g;                            \
        const int jj1 = jj0 + 4;                                          \
        const bool v0 = (jj0 < Wc);                                       \
        const bool v1 = (jj1 < Wc);                                       \
        const int jc0 = v0 ? jj0 : (Wc - 1);                              \
        const int jc1 = v1 ? jj1 : (Wc - 1);                              \
        float acc0 = edge_logit(A0, C0, UI0, UJ0, R0, Wf, Bvf, Owf);      \
        float acc1 = edge_logit(A1, C1, UI1, UJ1, R1, Wf, Bvf, Owf);      \
        _Pragma("unroll")                                                 \
        for (int off = 8; off > 0; off >>= 1) {                           \
            acc0 += __shfl_xor(acc0, off, 64);                            \
            acc1 += __shfl_xor(acc1, off, 64);                            \
        }                                                                 \
        if (d16 == 0) {                                                   \
            if (v0) { s_logit[jj0] = acc0; s_ivi[jj0] = s_sel[jc0 * 8 + 4]; } \
            if (v1) { s_logit[jj1] = acc1; s_ivi[jj1] = s_sel[jc1 * 8 + 4]; } \
        }                                                                 \
    }

// Scheduling fence: forbid the compiler from sinking prefetch loads past this
// point (rounds 3-5 lesson: without it, hipcc re-serializes the pipeline —
// VGPR_Count stayed at 72, i.e. prefetched values were never kept live).
#define SCHED_FENCE() __builtin_amdgcn_sched_barrier(0)

// ---------------- K1: fused logits + segment softmax + scatter + rowsum --------
// Round-2 lesson: no min-waves clause (forcing VGPR<=64 spilled -> 5x regression).
__global__ __launch_bounds__(256) void k_fused(
    const int* __restrict__ sel, const float* __restrict__ hc,
    const float* __restrict__ hu, const float* __restrict__ re,
    const float* __restrict__ wsm, const float* __restrict__ bias,
    const float* __restrict__ out_w,
    const float* __restrict__ na, const float* __restrict__ edges_y,
    float* __restrict__ out, float* __restrict__ row_sum,
    int E, int N)
{
    __shared__ int   s_sel[WSZ * 8];     // full sel rows for window
    __shared__ float s_logit[WSZ];
    __shared__ int   s_ivi[WSZ];         // dense idx_vi for stride-1 phase-B scans
    __shared__ float s_row[8];

    const int b0 = blockIdx.x * CH;
    const int Wc = min(WSZ, E - b0);     // valid edges in this window

    // ---------- Preload sel window (perfectly coalesced) ----------
    {
        const int nint = Wc * 8;
        const int* selw = sel + (size_t)b0 * 8;
        for (int i = threadIdx.x; i < nint; i += 256) s_sel[i] = selw[i];
    }
    if (threadIdx.x < 8) s_row[threadIdx.x] = 0.f;

    const int lane = threadIdx.x & 63;
    const int g    = lane >> 4;          // edge-group within wave (0..3)
    const int d16  = lane & 15;          // lane within group; d = d16*4 .. +3
    const int wv   = threadIdx.x >> 6;   // wave within block (0..3)

    // hoist constants into registers
    const float4* wsm4 = (const float4*)wsm;
    float4 Wk[8];
    #pragma unroll
    for (int k = 0; k < 8; ++k) Wk[k] = wsm4[k * 16 + d16];
    const float4 Bv = ((const float4*)bias)[d16];
    const float4 Ow = ((const float4*)out_w)[d16];
    const float* Wf  = (const float*)Wk;
    const float* Bvf = (const float*)&Bv;
    const float* Owf = (const float*)&Ow;

    const float4* hc4 = (const float4*)hc;
    const float4* hu4 = (const float4*)hu;
    const float4* re4 = (const float4*)re;

    __syncthreads();

    // ---------- Phase A: software-pipelined, sched_barrier-pinned ----------
    // Steady state per wave: 10-20 loads in flight (vs ~2 when the compiler
    // serializes). Waits are vmcnt(10), never a drain.
    float4 nA0a, nUI0a, nR0a, nA1a, nUI1a, nR1a, fC0a, fUJ0a, fC1a, fUJ1a;
    float4 nA0b, nUI0b, nR0b, nA1b, nUI1b, nR1b, fC0b, fUJ0b, fC1b, fUJ1b;

    ISSUE(nA0a, nUI0a, nR0a, nA1a, nUI1a, nR1a, fC0a, fUJ0a, fC1a, fUJ1a, 0);
    SCHED_FENCE();

    int t = 0;
    #pragma unroll 1
    for (; t + 1 < NT; t += 2) {
        ISSUE(nA0b, nUI0b, nR0b, nA1b, nUI1b, nR1b, fC0b, fUJ0b, fC1b, fUJ1b, t + 1);
        SCHED_FENCE();
        COMPUTE(nA0a, nUI0a, nR0a, nA1a, nUI1a, nR1a, fC0a, fUJ0a, fC1a, fUJ1a, t);
        SCHED_FENCE();
        ISSUE(nA0a, nUI0a, nR0a, nA1a, nUI1a, nR1a, fC0a, fUJ0a, fC1a, fUJ1a, t + 2);
        SCHED_FENCE();
        COMPUTE(nA0b, nUI0b, nR0b, nA1b, nUI1b, nR1b, fC0b, fUJ0b, fC1b, fUJ1b, t + 1);
        SCHED_FENCE();
    }
    // NT = 9 (odd): one iteration remains, its data already in buffer A
    COMPUTE(nA0a, nUI0a, nR0a, nA1a, nUI1a, nR1a, fC0a, fUJ0a, fC1a, fUJ1a, NT - 1);

    __syncthreads();

    // ---------- Phase B: block-local segment softmax + scatter ----------
    const int ivi_prev = (b0 > 0) ? sel[((size_t)b0 - 1) * 8 + 4] : -1;

    for (int j = threadIdx.x; j < Wc; j += 256) {
        const int myivi = s_ivi[j];

        int s = j;
        while (s > 0 && s_ivi[s - 1] == myivi) --s;
        const bool genuine = (s > 0) || (myivi != ivi_prev);
        if (!genuine || s >= CH) continue;      // segment owned by another block

        int en = j + 1;
        while (en < Wc && s_ivi[en] == myivi) ++en;

        float m = s_logit[j];
        for (int i = s; i < en; ++i) m = fmaxf(m, s_logit[i]);
        float sum = 0.f;
        for (int i = s; i < en; ++i) sum += __expf(s_logit[i] - m);

        const int idx = s_sel[j * 8 + 0];
        const int vi  = s_sel[j * 8 + 1];
        const int vj  = s_sel[j * 8 + 2];
        const float ta = na[(size_t)idx * N + vi]
                       * (__expf(s_logit[j] - m) / sum) * edges_y[b0 + j];

        atomicAdd(out + (size_t)idx * N + vj, ta);
        if (idx < 8) atomicAdd(&s_row[idx], ta);
        else         atomicAdd(row_sum + idx, ta);
    }

    __syncthreads();
    if (threadIdx.x < 8) {
        const float v = s_row[threadIdx.x];
        if (v != 0.f) atomicAdd(row_sum + threadIdx.x, v);
    }
}

// ---------------- K4: normalize rows (float4, 2D grid) ----------------
__global__ void k_norm(float4* __restrict__ out, const float* __restrict__ row_sum, int N4) {
    const int col = blockIdx.x * blockDim.x + threadIdx.x;
    const int row = blockIdx.y;
    if (col < N4) {
        const float inv = 1.f / row_sum[row];
        const size_t i = (size_t)row * N4 + col;
        float4 v = out[i];
        v.x *= inv; v.y *= inv; v.z *= inv; v.w *= inv;
        out[i] = v;
    }
}

extern "C" void kernel_launch(void* const* d_in, const int* in_sizes, int n_in,
                              void* d_out, int out_size, void* d_ws, size_t ws_size,
                              hipStream_t stream)
{
    const float* na    = (const float*)d_in[0];   // (B,N)
    const int*   sel   = (const int*)  d_in[1];   // (E,8)
    const float* ey    = (const float*)d_in[2];   // (E,)
    const float* hc    = (const float*)d_in[3];   // (n_visited, D)
    const float* hu    = (const float*)d_in[4];   // (1,N,D)
    const float* re    = (const float*)d_in[5];   // (R,D)
    const float* wsm   = (const float*)d_in[6];   // (8,D)
    const float* bias  = (const float*)d_in[7];   // (D,)
    const float* ow    = (const float*)d_in[8];   // (D,)
    // d_in[9] (out_b) intentionally unused: constant logit shift, softmax-invariant

    float* out = (float*)d_out;

    const int E  = in_sizes[2];
    const int N  = in_sizes[4] / D;   // hidden_uncon = N*D
    const int BN = in_sizes[0];       // B*N
    const int Bn = BN / N;

    float* row_sum = (float*)d_ws;

    const int N4  = N / 4;
    const int BN4 = BN / 4;

    k_zero<<<(BN4 + 255) / 256, 256, 0, stream>>>((float4*)out, row_sum, BN4, Bn);

    const int nblk = (E + CH - 1) / CH;
    k_fused<<<nblk, 256, 0, stream>>>(sel, hc, hu, re, wsm, bias, ow,
                                      na, ey, out, row_sum, E, N);

    dim3 ngrid((N4 + 255) / 256, Bn);
    k_norm<<<ngrid, 256, 0, stream>>>((float4*)out, row_sum, N4);
}